// Round 1
// baseline (229.738 us; speedup 1.0000x reference)
//
#include <hip/hip_runtime.h>
#include <hip/hip_bf16.h>
#include <stdint.h>

#define IN_SZ   256
#define OUT_SZ  256
#define RANK    60
#define NSEL    256
#define BATCH   1024
#define WELEMS  (IN_SZ * OUT_SZ)   // 65536 elems per channel

typedef __attribute__((ext_vector_type(8))) short          short8;
typedef __attribute__((ext_vector_type(4))) float          f32x4;
typedef __attribute__((ext_vector_type(4))) unsigned short u16x4;

static __device__ __forceinline__ unsigned short f32_to_bf16(float f) {
    union { float f; uint32_t u; } c; c.f = f;
    uint32_t u = c.u;
    u += 0x7fffu + ((u >> 16) & 1u);   // RNE
    return (unsigned short)(u >> 16);
}

// -----------------------------------------------------------------------------
// Kernel 1: W_sel[n] = U[idx[n]] @ V  -> bf16, stored per n in the LDS image
// layout kernel 2 stages with global_load_lds:
//   elem offset within n-image = ic*2048 + ((o ^ (ic&3)) * 8) + il
// where i = ic*8 + il (ic in 0..31), o in 0..255.  The (ic&3) XOR on the 16B
// slot index makes kernel 2's B-fragment ds_read_b128 bank-conflict-free.
// Block: 256 threads (thread = o), handles 8 channels (G=8) x one 8-i chunk.
// -----------------------------------------------------------------------------
__global__ __launch_bounds__(256) void synth_w(
    const float* __restrict__ U, const float* __restrict__ V,
    const int* __restrict__ idx, unsigned short* __restrict__ wt)
{
    __shared__ float Us[8][RANK];

    int bid = blockIdx.x;                  // 1024 blocks, %8==0 -> bijective swizzle
    int L   = (bid & 7) * 128 + (bid >> 3);
    int ic  = L >> 5;                      // 0..31  i-chunk (same-ic blocks share V slice -> same XCD)
    int ng  = L & 31;                      // 0..31  n-group

    int tid = threadIdx.x;
    for (int t = tid; t < 8 * RANK; t += 256) {
        int g = t / RANK, r = t % RANK;
        int c = idx[ng * 8 + g];
        Us[g][r] = U[c * RANK + r];
    }
    __syncthreads();

    int o  = tid;
    int i0 = ic * 8;
    float wb[8][8];                        // [g][il] — all indices static after unroll

    #pragma unroll
    for (int il = 0; il < 8; ++il) {
        const float* vp = V + (size_t)(i0 + il) * OUT_SZ + o;
        float a[8] = {0.f,0.f,0.f,0.f,0.f,0.f,0.f,0.f};
        for (int r = 0; r < RANK; ++r) {
            float v = vp[(size_t)r * WELEMS];
            #pragma unroll
            for (int g = 0; g < 8; ++g) a[g] = fmaf(Us[g][r], v, a[g]);
        }
        #pragma unroll
        for (int g = 0; g < 8; ++g) wb[g][il] = a[g];
    }

    int slot = o ^ (ic & 3);
    size_t base = (size_t)ic * 2048 + (size_t)slot * 8;
    #pragma unroll
    for (int g = 0; g < 8; ++g) {
        int n = ng * 8 + g;
        short8 h;
        #pragma unroll
        for (int j = 0; j < 8; ++j) h[j] = (short)f32_to_bf16(wb[g][j]);
        *reinterpret_cast<short8*>(wt + (size_t)n * WELEMS + base) = h;
    }
}

// -----------------------------------------------------------------------------
// Kernel 2: out[n] = x[n] @ W_sel[n] + bias[idx[n]]
// BM=64, BN=256 (full width -> x read once), BK=64, 256 threads = 4 waves,
// wave w owns cols [w*64, w*64+64), 4x4 frags of mfma_f32_16x16x32_bf16.
// A: reg-staged f32->bf16 into LDS with (row&7)<<4 XOR swizzle.
// B: global_load_lds (16B/lane) of the pre-swizzled image from kernel 1.
// -----------------------------------------------------------------------------
__global__ __launch_bounds__(256) void gemm_k(
    const float* __restrict__ x, const int* __restrict__ idx,
    const unsigned short* __restrict__ wt, const float* __restrict__ bias,
    float* __restrict__ out)
{
    __shared__ __align__(16) unsigned short As[64 * 64];        // 8 KB
    __shared__ __align__(16) unsigned short Bs[8 * 256 * 8];    // 32 KB

    int bid = blockIdx.x;                  // 4096 blocks
    int L   = (bid & 7) * 512 + (bid >> 3);
    int n   = L >> 4;                      // same-n m-tiles -> same XCD (W[n] L2-resident)
    int mt  = L & 15;

    int tid  = threadIdx.x;
    int lane = tid & 63;
    int wv   = tid >> 6;                   // wave id 0..3

    const float*          xn = x  + (size_t)n * (BATCH * IN_SZ) + (size_t)mt * 64 * IN_SZ;
    const unsigned short* wn = wt + (size_t)n * WELEMS;

    f32x4 acc[4][4] = {};

    for (int kt = 0; kt < 4; ++kt) {
        if (kt) __syncthreads();           // protect LDS reuse

        // ---- stage A: 64x64 f32 -> bf16, swizzled ----
        #pragma unroll
        for (int p = 0; p < 4; ++p) {
            int id  = tid + p * 256;
            int row = id >> 4;             // 0..63
            int c4  = id & 15;             // 16B chunk within row
            float4 v = *reinterpret_cast<const float4*>(
                xn + (size_t)row * IN_SZ + kt * 64 + c4 * 4);
            u16x4 h;
            h[0] = f32_to_bf16(v.x); h[1] = f32_to_bf16(v.y);
            h[2] = f32_to_bf16(v.z); h[3] = f32_to_bf16(v.w);
            int off = row * 128 + ((c4 * 8) ^ ((row & 7) << 4));   // bytes
            *reinterpret_cast<u16x4*>(&As[off >> 1]) = h;
        }

        // ---- stage B: 32KB linear copy of the pre-swizzled image ----
        #pragma unroll
        for (int p = 0; p < 8; ++p) {
            int seg = wv * 8 + p;          // 0..31, 1KB per wave-call
            const unsigned short* gp = wn + (size_t)kt * 16384 + (size_t)seg * 512 + lane * 8;
            __builtin_amdgcn_global_load_lds(
                (const __attribute__((address_space(1))) void*)gp,
                (__attribute__((address_space(3))) void*)(&Bs[seg * 512]),
                16, 0, 0);
        }
        __syncthreads();

        // ---- MFMA: 2 sub-K of 32, 16 mfma each ----
        #pragma unroll
        for (int kk = 0; kk < 2; ++kk) {
            short8 af[4], bf[4];
            int krow = kk * 32 + (lane >> 4) * 8;      // k within BK=64
            #pragma unroll
            for (int mf = 0; mf < 4; ++mf) {
                int row = mf * 16 + (lane & 15);
                int off = row * 128 + ((krow * 2) ^ ((row & 7) << 4));
                af[mf] = *reinterpret_cast<const short8*>(&As[off >> 1]);
            }
            int gi = kk * 4 + (lane >> 4);             // 16-lane-group k-block 0..7
            #pragma unroll
            for (int nf = 0; nf < 4; ++nf) {
                int o   = wv * 64 + nf * 16 + (lane & 15);
                int off = gi * 4096 + ((o ^ (gi & 3)) * 16);       // bytes
                bf[nf] = *reinterpret_cast<const short8*>(&Bs[off >> 1]);
            }
            #pragma unroll
            for (int mf = 0; mf < 4; ++mf)
                #pragma unroll
                for (int nf = 0; nf < 4; ++nf)
                    acc[mf][nf] = __builtin_amdgcn_mfma_f32_16x16x32_bf16(
                        af[mf], bf[nf], acc[mf][nf], 0, 0, 0);
        }
    }

    // ---- epilogue: + bias, store f32 ----
    int c = idx[n];
    float bv[4];
    #pragma unroll
    for (int nf = 0; nf < 4; ++nf)
        bv[nf] = bias[(size_t)c * OUT_SZ + wv * 64 + nf * 16 + (lane & 15)];

    float* on = out + (size_t)n * (BATCH * OUT_SZ) + (size_t)mt * 64 * OUT_SZ;
    #pragma unroll
    for (int mf = 0; mf < 4; ++mf) {
        int r0 = mf * 16 + (lane >> 4) * 4;
        #pragma unroll
        for (int nf = 0; nf < 4; ++nf) {
            int o = wv * 64 + nf * 16 + (lane & 15);
            #pragma unroll
            for (int j = 0; j < 4; ++j)
                on[(size_t)(r0 + j) * OUT_SZ + o] = acc[mf][nf][j] + bv[nf];
        }
    }
}

extern "C" void kernel_launch(void* const* d_in, const int* in_sizes, int n_in,
                              void* d_out, int out_size, void* d_ws, size_t ws_size,
                              hipStream_t stream) {
    const float* x    = (const float*)d_in[0];
    const int*   idx  = (const int*)  d_in[1];
    const float* U    = (const float*)d_in[2];
    const float* V    = (const float*)d_in[3];
    const float* bias = (const float*)d_in[4];
    float* out = (float*)d_out;
    unsigned short* wt = (unsigned short*)d_ws;   // 256*65536*2 = 32 MB scratch
    (void)in_sizes; (void)n_in; (void)out_size; (void)ws_size;

    synth_w<<<dim3(1024), dim3(256), 0, stream>>>(U, V, idx, wt);
    gemm_k <<<dim3(4096), dim3(256), 0, stream>>>(x, idx, wt, bias, out);
}

// Round 2
// 182.190 us; speedup vs baseline: 1.2610x; 1.2610x over previous
//
#include <hip/hip_runtime.h>
#include <hip/hip_bf16.h>
#include <stdint.h>

#define IN_SZ   256
#define OUT_SZ  256
#define RANK    60
#define NSEL    256
#define BATCH   1024
#define WELEMS  (IN_SZ * OUT_SZ)   // 65536 elems per channel

typedef __attribute__((ext_vector_type(8))) short          short8;
typedef __attribute__((ext_vector_type(4))) float          f32x4;
typedef __attribute__((ext_vector_type(4))) unsigned short u16x4;

static __device__ __forceinline__ unsigned short f32_to_bf16(float f) {
    union { float f; uint32_t u; } c; c.f = f;
    uint32_t u = c.u;
    u += 0x7fffu + ((u >> 16) & 1u);   // RNE
    return (unsigned short)(u >> 16);
}

// -----------------------------------------------------------------------------
// Kernel 1 (MFMA rewrite): W_sel = U[idx] @ V -> bf16 in the pre-swizzled
// layout gemm_k consumes:  elem offset in n-image = ic*2048 + ((o^(ic&3))*8) + il
// where i = ic*8+il.  Block = (g16, ic): 16 selected channels (M=16) x one
// 2048-wide flat-m chunk (= 8 i-rows x 256 o).  K = 60 padded to 64.
// C-tiles go through an LDS transpose so stores are contiguous short8.
// -----------------------------------------------------------------------------
__global__ __launch_bounds__(256) void synth_w(
    const float* __restrict__ U, const float* __restrict__ V,
    const int* __restrict__ idx, unsigned short* __restrict__ wt)
{
    __shared__ unsigned short Cs[16][2064];   // +16 pad: conflict-free C writes

    int bid = blockIdx.x;                  // 512 blocks
    int L   = (bid & 7) * 64 + (bid >> 3); // XCD swizzle: same-ic -> same XCD
    int ic  = L >> 4;                      // 0..31
    int g16 = L & 15;                      // 0..15 (n-group of 16)

    int tid = threadIdx.x, lane = tid & 63, wv = tid >> 6;

    // ---- A fragments: 16 channels x 64 k (zero-padded past RANK) ----
    int arow = lane & 15;
    int c    = idx[g16 * 16 + arow];
    short8 afr[2];
    #pragma unroll
    for (int ks = 0; ks < 2; ++ks) {
        short8 h;
        #pragma unroll
        for (int j = 0; j < 8; ++j) {
            int r = ks * 32 + (lane >> 4) * 8 + j;
            float u = (r < RANK) ? U[c * RANK + r] : 0.f;
            h[j] = (short)f32_to_bf16(u);
        }
        afr[ks] = h;
    }

    // ---- stream B = V[k][m] column tiles, MFMA, park C in LDS ----
    const float* Vb = V + (size_t)ic * 2048;
    #pragma unroll 2
    for (int mt = 0; mt < 32; ++mt) {
        int mloc = (wv * 32 + mt) * 16 + (lane & 15);
        f32x4 acc = {};
        #pragma unroll
        for (int ks = 0; ks < 2; ++ks) {
            short8 b;
            #pragma unroll
            for (int j = 0; j < 8; ++j) {
                int r = ks * 32 + (lane >> 4) * 8 + j;
                float v = (r < RANK) ? Vb[(size_t)r * WELEMS + mloc] : 0.f;
                b[j] = (short)f32_to_bf16(v);
            }
            acc = __builtin_amdgcn_mfma_f32_16x16x32_bf16(afr[ks], b, acc, 0, 0, 0);
        }
        #pragma unroll
        for (int j = 0; j < 4; ++j) {
            int nl = (lane >> 4) * 4 + j;
            Cs[nl][wv * 512 + mt * 16 + (lane & 15)] = f32_to_bf16(acc[j]);
        }
    }
    __syncthreads();

    // ---- store: per (n, o) pack il=0..7 into one short8 at swizzled slot ----
    #pragma unroll
    for (int t0 = 0; t0 < 16; ++t0) {
        int t  = t0 * 256 + tid;
        int nl = t >> 8;
        int o  = t & 255;
        short8 h;
        #pragma unroll
        for (int il = 0; il < 8; ++il) h[il] = (short)Cs[nl][il * 256 + o];
        int n = g16 * 16 + nl;
        size_t base = (size_t)n * WELEMS + (size_t)ic * 2048 + (size_t)((o ^ (ic & 3)) * 8);
        *reinterpret_cast<short8*>(wt + base) = h;
    }
}

// -----------------------------------------------------------------------------
// Kernel 2: out[n] = x[n] @ W_sel[n] + bias[idx[n]]
// BM=64, BN=256, BK=64, 4 waves. Double-buffered LDS + T3-min 2-phase:
// issue stage(t+1) BEFORE compute(t); one barrier per K-step.
// -----------------------------------------------------------------------------
__global__ __launch_bounds__(256) void gemm_k(
    const float* __restrict__ x, const int* __restrict__ idx,
    const unsigned short* __restrict__ wt, const float* __restrict__ bias,
    float* __restrict__ out)
{
    __shared__ __align__(16) unsigned short As[2][64 * 64];     // 2 x  8 KB
    __shared__ __align__(16) unsigned short Bs[2][8 * 256 * 8]; // 2 x 32 KB

    int bid = blockIdx.x;                  // 4096 blocks
    int L   = (bid & 7) * 512 + (bid >> 3);
    int n   = L >> 4;                      // same-n m-tiles -> same XCD
    int mt  = L & 15;

    int tid  = threadIdx.x;
    int lane = tid & 63;
    int wv   = tid >> 6;

    const float*          xn = x  + (size_t)n * (BATCH * IN_SZ) + (size_t)mt * 64 * IN_SZ;
    const unsigned short* wn = wt + (size_t)n * WELEMS;

    f32x4 acc[4][4] = {};

    // A-row/chunk for this thread's 4 staging pieces
    auto stageA_load = [&](int kt, float4* va) {
        #pragma unroll
        for (int p = 0; p < 4; ++p) {
            int id  = tid + p * 256;
            int row = id >> 4, c4 = id & 15;
            va[p] = *reinterpret_cast<const float4*>(
                xn + (size_t)row * IN_SZ + kt * 64 + c4 * 4);
        }
    };
    auto stageA_write = [&](int buf, const float4* va) {
        #pragma unroll
        for (int p = 0; p < 4; ++p) {
            int id  = tid + p * 256;
            int row = id >> 4, c4 = id & 15;
            u16x4 h;
            h[0] = f32_to_bf16(va[p].x); h[1] = f32_to_bf16(va[p].y);
            h[2] = f32_to_bf16(va[p].z); h[3] = f32_to_bf16(va[p].w);
            int off = row * 128 + ((c4 * 8) ^ ((row & 7) << 4));   // bytes
            *reinterpret_cast<u16x4*>(&As[buf][off >> 1]) = h;
        }
    };
    auto stageB = [&](int buf, int kt) {
        #pragma unroll
        for (int p = 0; p < 8; ++p) {
            int seg = wv * 8 + p;
            const unsigned short* gp = wn + (size_t)kt * 16384 + (size_t)seg * 512 + lane * 8;
            __builtin_amdgcn_global_load_lds(
                (const __attribute__((address_space(1))) void*)gp,
                (__attribute__((address_space(3))) void*)(&Bs[buf][seg * 512]),
                16, 0, 0);
        }
    };
    auto compute = [&](int buf) {
        #pragma unroll
        for (int kk = 0; kk < 2; ++kk) {
            short8 af[4], bf[4];
            int krow = kk * 32 + (lane >> 4) * 8;
            #pragma unroll
            for (int mf = 0; mf < 4; ++mf) {
                int row = mf * 16 + (lane & 15);
                int off = row * 128 + ((krow * 2) ^ ((row & 7) << 4));
                af[mf] = *reinterpret_cast<const short8*>(&As[buf][off >> 1]);
            }
            int gi = kk * 4 + (lane >> 4);
            #pragma unroll
            for (int nf = 0; nf < 4; ++nf) {
                int o   = wv * 64 + nf * 16 + (lane & 15);
                int off = gi * 4096 + ((o ^ (gi & 3)) * 16);
                bf[nf] = *reinterpret_cast<const short8*>(&Bs[buf][off >> 1]);
            }
            #pragma unroll
            for (int mf = 0; mf < 4; ++mf)
                #pragma unroll
                for (int nf = 0; nf < 4; ++nf)
                    acc[mf][nf] = __builtin_amdgcn_mfma_f32_16x16x32_bf16(
                        af[mf], bf[nf], acc[mf][nf], 0, 0, 0);
        }
    };

    // prologue: fill buf 0
    {
        float4 va[4];
        stageA_load(0, va);
        stageB(0, 0);
        stageA_write(0, va);
    }
    __syncthreads();   // compiler drains vmcnt/lgkm here — buf0 ready

    int cur = 0;
    #pragma unroll
    for (int kt = 0; kt < 4; ++kt) {
        float4 va[4];
        if (kt < 3) {
            stageA_load(kt + 1, va);   // issue next-tile loads first
            stageB(cur ^ 1, kt + 1);   // DMA into other buffer
        }
        compute(cur);                  // overlaps the in-flight loads
        if (kt < 3) stageA_write(cur ^ 1, va);
        __syncthreads();               // drain -> next buffer ready
        cur ^= 1;
    }

    // ---- epilogue: + bias, store f32 ----
    int c = idx[n];
    float bv[4];
    #pragma unroll
    for (int nf = 0; nf < 4; ++nf)
        bv[nf] = bias[(size_t)c * OUT_SZ + wv * 64 + nf * 16 + (lane & 15)];

    float* on = out + (size_t)n * (BATCH * OUT_SZ) + (size_t)mt * 64 * OUT_SZ;
    #pragma unroll
    for (int mf = 0; mf < 4; ++mf) {
        int r0 = mf * 16 + (lane >> 4) * 4;
        #pragma unroll
        for (int nf = 0; nf < 4; ++nf) {
            int o = wv * 64 + nf * 16 + (lane & 15);
            #pragma unroll
            for (int j = 0; j < 4; ++j)
                on[(size_t)(r0 + j) * OUT_SZ + o] = acc[mf][nf][j] + bv[nf];
        }
    }
}

extern "C" void kernel_launch(void* const* d_in, const int* in_sizes, int n_in,
                              void* d_out, int out_size, void* d_ws, size_t ws_size,
                              hipStream_t stream) {
    const float* x    = (const float*)d_in[0];
    const int*   idx  = (const int*)  d_in[1];
    const float* U    = (const float*)d_in[2];
    const float* V    = (const float*)d_in[3];
    const float* bias = (const float*)d_in[4];
    float* out = (float*)d_out;
    unsigned short* wt = (unsigned short*)d_ws;   // 32 MB scratch
    (void)in_sizes; (void)n_in; (void)out_size; (void)ws_size;

    synth_w<<<dim3(512),  dim3(256), 0, stream>>>(U, V, idx, wt);
    gemm_k <<<dim3(4096), dim3(256), 0, stream>>>(x, idx, wt, bias, out);
}

// Round 3
// 171.376 us; speedup vs baseline: 1.3405x; 1.0631x over previous
//
#include <hip/hip_runtime.h>
#include <hip/hip_bf16.h>
#include <stdint.h>

#define IN_SZ   256
#define OUT_SZ  256
#define RANK    60
#define NSEL    256
#define BATCH   1024
#define WELEMS  (IN_SZ * OUT_SZ)   // 65536 elems per channel

typedef __attribute__((ext_vector_type(8))) short          short8;
typedef __attribute__((ext_vector_type(4))) float          f32x4;
typedef __attribute__((ext_vector_type(4))) unsigned short u16x4;

static __device__ __forceinline__ unsigned short f32_to_bf16(float f) {
    union { float f; uint32_t u; } c; c.f = f;
    uint32_t u = c.u;
    u += 0x7fffu + ((u >> 16) & 1u);   // RNE
    return (unsigned short)(u >> 16);
}

// -----------------------------------------------------------------------------
// Kernel 1: W_sel = U[idx] @ V -> bf16 in B-FRAGMENT-MAJOR layout:
//   wt[n][(i>>3)*2048 + o*8 + (i&7)]
// i.e. per n, per i-octet (32 of them), 256 cols x 8 consecutive-i bf16 (16B).
// gemm_k loads B-fragments with a single perfectly-coalesced dwordx4.
// Block = (g16, ic): 16 channels (M=16 MFMA) x one i-octet chunk (8 i x 256 o).
// -----------------------------------------------------------------------------
__global__ __launch_bounds__(256) void synth_w(
    const float* __restrict__ U, const float* __restrict__ V,
    const int* __restrict__ idx, unsigned short* __restrict__ wt)
{
    __shared__ unsigned short Cs[16][2064];   // +16 pad: conflict-free transpose

    int bid = blockIdx.x;                  // 512 blocks
    int L   = (bid & 7) * 64 + (bid >> 3); // XCD swizzle: same-ic -> same XCD
    int ic  = L >> 4;                      // 0..31
    int g16 = L & 15;                      // 0..15

    int tid = threadIdx.x, lane = tid & 63, wv = tid >> 6;

    // A fragments: 16 channels x 64 k (zero-padded past RANK=60)
    int arow = lane & 15;
    int c    = idx[g16 * 16 + arow];
    short8 afr[2];
    #pragma unroll
    for (int ks = 0; ks < 2; ++ks) {
        short8 h;
        #pragma unroll
        for (int j = 0; j < 8; ++j) {
            int r = ks * 32 + (lane >> 4) * 8 + j;
            float u = (r < RANK) ? U[c * RANK + r] : 0.f;
            h[j] = (short)f32_to_bf16(u);
        }
        afr[ks] = h;
    }

    const float* Vb = V + (size_t)ic * 2048;
    #pragma unroll 2
    for (int mt = 0; mt < 32; ++mt) {
        int mloc = (wv * 32 + mt) * 16 + (lane & 15);
        f32x4 acc = {};
        #pragma unroll
        for (int ks = 0; ks < 2; ++ks) {
            short8 b;
            #pragma unroll
            for (int j = 0; j < 8; ++j) {
                int r = ks * 32 + (lane >> 4) * 8 + j;
                float v = (r < RANK) ? Vb[(size_t)r * WELEMS + mloc] : 0.f;
                b[j] = (short)f32_to_bf16(v);
            }
            acc = __builtin_amdgcn_mfma_f32_16x16x32_bf16(afr[ks], b, acc, 0, 0, 0);
        }
        #pragma unroll
        for (int j = 0; j < 4; ++j) {
            int nl = (lane >> 4) * 4 + j;
            Cs[nl][wv * 512 + mt * 16 + (lane & 15)] = f32_to_bf16(acc[j]);
        }
    }
    __syncthreads();

    // store: per (n, o) pack il=0..7 into one short8 (fragment-major, no XOR)
    #pragma unroll
    for (int t0 = 0; t0 < 16; ++t0) {
        int t  = t0 * 256 + tid;
        int nl = t >> 8;
        int o  = t & 255;
        short8 h;
        #pragma unroll
        for (int il = 0; il < 8; ++il) h[il] = (short)Cs[nl][il * 256 + o];
        int n = g16 * 16 + nl;
        size_t base = (size_t)n * WELEMS + (size_t)ic * 2048 + (size_t)o * 8;
        *reinterpret_cast<short8*>(wt + base) = h;
    }
}

// -----------------------------------------------------------------------------
// Kernel 2: out[n] = x[n] @ W_sel[n] + bias[idx[n]]
// BM=64, BN=256, full K staged: A-tile (64x256 bf16, XOR-swizzled) in 32 KB LDS,
// ONE barrier per block, then 8 fully-unrolled K-steps of
// {4 ds_read_b128 A-frags, 4 coalesced global dwordx4 B-frags (L2-hot), 16 MFMA}.
// No Bs LDS, no main-loop barriers -> latency hidden by 12+ free-running waves.
// -----------------------------------------------------------------------------
__global__ __launch_bounds__(256, 3) void gemm_k(
    const float* __restrict__ x, const int* __restrict__ idx,
    const unsigned short* __restrict__ wt, const float* __restrict__ bias,
    float* __restrict__ out)
{
    __shared__ __align__(16) unsigned short As[64 * 256];   // 32 KB

    int bid = blockIdx.x;                  // 4096 blocks
    int L   = (bid & 7) * 512 + (bid >> 3);
    int n   = L >> 4;                      // 16 m-tiles of same n -> same XCD
    int mt  = L & 15;

    int tid  = threadIdx.x;
    int lane = tid & 63;
    int wv   = tid >> 6;
    int r16  = lane & 15;
    int q    = lane >> 4;

    const float*          xn = x  + (size_t)n * (BATCH * IN_SZ) + (size_t)mt * 64 * IN_SZ;
    const unsigned short* wb = wt + (size_t)n * WELEMS;

    // ---- stage x-tile: 64 rows x 256 f32 -> bf16, rows of 512B, XOR swizzle ----
    #pragma unroll
    for (int p = 0; p < 8; ++p) {
        int id    = p * 256 + tid;         // 2048 items of 8 floats
        int row   = id >> 5;
        int chunk = id & 31;
        const float* gp = xn + (size_t)row * IN_SZ + chunk * 8;
        float4 v0 = *reinterpret_cast<const float4*>(gp);
        float4 v1 = *reinterpret_cast<const float4*>(gp + 4);
        short8 h;
        h[0] = (short)f32_to_bf16(v0.x); h[1] = (short)f32_to_bf16(v0.y);
        h[2] = (short)f32_to_bf16(v0.z); h[3] = (short)f32_to_bf16(v0.w);
        h[4] = (short)f32_to_bf16(v1.x); h[5] = (short)f32_to_bf16(v1.y);
        h[6] = (short)f32_to_bf16(v1.z); h[7] = (short)f32_to_bf16(v1.w);
        int off = row * 512 + ((chunk * 16) ^ ((row & 7) << 4));   // bytes
        *reinterpret_cast<short8*>(&As[off >> 1]) = h;
    }
    __syncthreads();   // the only barrier

    f32x4 acc[4][4] = {};

    #pragma unroll
    for (int ks = 0; ks < 8; ++ks) {
        short8 af[4], bf[4];
        #pragma unroll
        for (int mf = 0; mf < 4; ++mf) {
            int row = mf * 16 + r16;
            int off = row * 512 + ((ks * 64 + q * 16) ^ ((row & 7) << 4));
            af[mf] = *reinterpret_cast<const short8*>(&As[off >> 1]);
        }
        #pragma unroll
        for (int nf = 0; nf < 4; ++nf) {
            int o = wv * 64 + nf * 16 + r16;
            bf[nf] = *reinterpret_cast<const short8*>(
                wb + (size_t)((ks * 4 + q) * 2048 + o * 8));
        }
        #pragma unroll
        for (int mf = 0; mf < 4; ++mf)
            #pragma unroll
            for (int nf = 0; nf < 4; ++nf)
                acc[mf][nf] = __builtin_amdgcn_mfma_f32_16x16x32_bf16(
                    af[mf], bf[nf], acc[mf][nf], 0, 0, 0);
    }

    // ---- epilogue: + bias, store f32 ----
    int c = idx[n];
    float bv[4];
    #pragma unroll
    for (int nf = 0; nf < 4; ++nf)
        bv[nf] = bias[(size_t)c * OUT_SZ + wv * 64 + nf * 16 + r16];

    float* on = out + (size_t)n * (BATCH * OUT_SZ) + (size_t)mt * 64 * OUT_SZ;
    #pragma unroll
    for (int mf = 0; mf < 4; ++mf) {
        int r0 = mf * 16 + q * 4;
        #pragma unroll
        for (int nf = 0; nf < 4; ++nf) {
            int o = wv * 64 + nf * 16 + r16;
            #pragma unroll
            for (int j = 0; j < 4; ++j)
                on[(size_t)(r0 + j) * OUT_SZ + o] = acc[mf][nf][j] + bv[nf];
        }
    }
}

extern "C" void kernel_launch(void* const* d_in, const int* in_sizes, int n_in,
                              void* d_out, int out_size, void* d_ws, size_t ws_size,
                              hipStream_t stream) {
    const float* x    = (const float*)d_in[0];
    const int*   idx  = (const int*)  d_in[1];
    const float* U    = (const float*)d_in[2];
    const float* V    = (const float*)d_in[3];
    const float* bias = (const float*)d_in[4];
    float* out = (float*)d_out;
    unsigned short* wt = (unsigned short*)d_ws;   // 32 MB scratch
    (void)in_sizes; (void)n_in; (void)out_size; (void)ws_size;

    synth_w<<<dim3(512),  dim3(256), 0, stream>>>(U, V, idx, wt);
    gemm_k <<<dim3(4096), dim3(256), 0, stream>>>(x, idx, wt, bias, out);
}